// Round 8
// baseline (46.167 us; speedup 1.0000x reference)
//
#include <hip/hip_runtime.h>
#include <stdint.h>

// YOLO v1 loss: BATCH=16384, S=7, B=2, C=20, D=30 floats per cell.
// NCELLS = 802816. Thread handles a PAIR of adjacent cells: 240 B = 15 x float4
// per tensor, 16B-aligned. 1568 blocks x 256 threads x 2 cells.
#define NCELLS 802816
#define NPAIRS 401408
#define GBLK 1568

__device__ __forceinline__ void merge2(unsigned& a1, unsigned& a2,
                                       unsigned b1, unsigned b2) {
    // (a1<=a2), (b1<=b2) -> two smallest of the union
    const unsigned n1 = min(a1, b1);
    const unsigned n2 = min(max(a1, b1), min(a2, b2));
    a1 = n1; a2 = n2;
}

// per-cell YOLO terms; pv/tv are the 30 floats of one cell
__device__ __forceinline__ void cell_terms(
    const float* pv, const float* tv, int cell,
    float& acc_loc, float& acc_hit, float& acc_noobj, float& acc_cls,
    unsigned& m1, unsigned& m2)
{
    const float obj = (tv[0] == 1.0f) ? 1.0f : 0.0f;

    // ---- class loss ----
    float cls = 0.0f;
#pragma unroll
    for (int i = 10; i < 30; ++i) { float d = pv[i] - tv[i]; cls = fmaf(d, d, cls); }
    acc_cls = fmaf(cls, obj, acc_cls);

    // ---- gt box 0 corners (mirrors reference arithmetic) ----
    const float g0x = tv[2] / 7.0f - 0.5f * tv[4];
    const float g0y = tv[3] / 7.0f - 0.5f * tv[5];
    const float g1x = tv[2] / 7.0f + 0.5f * tv[4];
    const float g1y = tv[3] / 7.0f + 0.5f * tv[5];
    const float area_g = (g1x - g0x) * (g1y - g0y);

    // ---- IoUs for both pred boxes vs gt box 0 ----
    float iou[2];
#pragma unroll
    for (int b = 0; b < 2; ++b) {
        const float px = pv[2 + 4*b], py = pv[3 + 4*b];
        const float pw = pv[4 + 4*b], ph = pv[5 + 4*b];
        const float a0x = px / 7.0f - 0.5f * pw, a0y = py / 7.0f - 0.5f * ph;
        const float a1x = px / 7.0f + 0.5f * pw, a1y = py / 7.0f + 0.5f * ph;
        const float ltx = fmaxf(a0x, g0x), lty = fmaxf(a0y, g0y);
        const float rbx = fminf(a1x, g1x), rby = fminf(a1y, g1y);
        const float ww = fmaxf(rbx - ltx, 0.0f), hh = fmaxf(rby - lty, 0.0f);
        const float inter  = ww * hh;
        const float area_a = (a1x - a0x) * (a1y - a0y);
        iou[b] = inter / (area_a + area_g - inter);
    }
    // jnp.argmax tie-break: first index wins
    const int resp = (iou[1] > iou[0]) ? 1 : 0;

#pragma unroll
    for (int b = 0; b < 2; ++b) {
        const bool m = (obj != 0.0f) && (b == resp);
        const float pc = pv[b];
        if (m) {
            const float d = pc - iou[b];
            acc_hit = fmaf(d, d, acc_hit);
            float sq = 0.0f;
#pragma unroll
            for (int i = 0; i < 4; ++i) {
                const float a = pv[2 + 4*b + i], g = tv[2 + 4*b + i];
                const float ds = sqrtf(a) - sqrtf(g);
                sq = fmaf(ds, ds, sq);
            }
            acc_loc += sq;
            merge2(m1, m2, (unsigned)(cell * 2 + b), 0xFFFFFFFFu);
        } else {
            acc_noobj = fmaf(pc, pc, acc_noobj);
        }
    }
}

// ws layout (SoA, every slot written every call):
//   float sums[4][GBLK]  at float offset 0       (loc_sq, hit, noobj, cls)
//   uint  mins[2][GBLK]  at float offset 4*GBLK  (min, second-min contained idx)

__global__ __launch_bounds__(256) void yolo_main_kernel(
    const float* __restrict__ pred, const float* __restrict__ targ,
    float* __restrict__ ws_sums, unsigned* __restrict__ ws_mins)
{
    const int tid  = threadIdx.x;
    const int pair = blockIdx.x * 256 + tid;          // 2 cells per thread
    const int cell = pair * 2;

    // ---- direct-to-register loads: 15 float4 per tensor (240 B, 16B-aligned) ----
    float pv[60], tv[60];
    const float4* p4 = reinterpret_cast<const float4*>(pred) + (size_t)pair * 15;
    const float4* t4 = reinterpret_cast<const float4*>(targ) + (size_t)pair * 15;
#pragma unroll
    for (int i = 0; i < 15; ++i) {
        const float4 v = p4[i];
        pv[4*i] = v.x; pv[4*i+1] = v.y; pv[4*i+2] = v.z; pv[4*i+3] = v.w;
    }
#pragma unroll
    for (int i = 0; i < 15; ++i) {
        const float4 v = t4[i];
        tv[4*i] = v.x; tv[4*i+1] = v.y; tv[4*i+2] = v.z; tv[4*i+3] = v.w;
    }

    float acc_loc = 0.0f, acc_hit = 0.0f, acc_noobj = 0.0f, acc_cls = 0.0f;
    unsigned m1 = 0xFFFFFFFFu, m2 = 0xFFFFFFFFu;

    cell_terms(pv,      tv,      cell,     acc_loc, acc_hit, acc_noobj, acc_cls, m1, m2);
    cell_terms(pv + 30, tv + 30, cell + 1, acc_loc, acc_hit, acc_noobj, acc_cls, m1, m2);

    // ---- block reduction (LDS tree) ----
    __shared__ float sred[4][256];
    __shared__ unsigned sm1[256], sm2[256];
    sred[0][tid] = acc_loc; sred[1][tid] = acc_hit;
    sred[2][tid] = acc_noobj; sred[3][tid] = acc_cls;
    sm1[tid] = m1; sm2[tid] = m2;
    __syncthreads();
#pragma unroll
    for (int s = 128; s > 0; s >>= 1) {
        if (tid < s) {
            sred[0][tid] += sred[0][tid + s];
            sred[1][tid] += sred[1][tid + s];
            sred[2][tid] += sred[2][tid + s];
            sred[3][tid] += sred[3][tid + s];
            unsigned a1 = sm1[tid], a2 = sm2[tid];
            merge2(a1, a2, sm1[tid + s], sm2[tid + s]);
            sm1[tid] = a1; sm2[tid] = a2;
        }
        __syncthreads();
    }
    if (tid == 0) {
        ws_sums[0 * GBLK + blockIdx.x] = sred[0][0];
        ws_sums[1 * GBLK + blockIdx.x] = sred[1][0];
        ws_sums[2 * GBLK + blockIdx.x] = sred[2][0];
        ws_sums[3 * GBLK + blockIdx.x] = sred[3][0];
        ws_mins[0 * GBLK + blockIdx.x] = sm1[0];
        ws_mins[1 * GBLK + blockIdx.x] = sm2[0];
    }
}

__global__ __launch_bounds__(1024) void yolo_finalize_kernel(
    const float* __restrict__ pred, const float* __restrict__ targ,
    const float* __restrict__ ws_sums, const unsigned* __restrict__ ws_mins,
    float* __restrict__ out)
{
    const int tid = threadIdx.x;
    double s0 = 0.0, s1 = 0.0, s2 = 0.0, s3 = 0.0;
    unsigned m1 = 0xFFFFFFFFu, m2 = 0xFFFFFFFFu;
    for (int i = tid; i < GBLK; i += 1024) {
        s0 += (double)ws_sums[0 * GBLK + i];
        s1 += (double)ws_sums[1 * GBLK + i];
        s2 += (double)ws_sums[2 * GBLK + i];
        s3 += (double)ws_sums[3 * GBLK + i];
        merge2(m1, m2, ws_mins[0 * GBLK + i], ws_mins[1 * GBLK + i]);
    }
    __shared__ double dred[4][1024];
    __shared__ unsigned fm1[1024], fm2[1024];
    dred[0][tid] = s0; dred[1][tid] = s1; dred[2][tid] = s2; dred[3][tid] = s3;
    fm1[tid] = m1; fm2[tid] = m2;
    __syncthreads();
#pragma unroll
    for (int s = 512; s > 0; s >>= 1) {
        if (tid < s) {
            dred[0][tid] += dred[0][tid + s];
            dred[1][tid] += dred[1][tid + s];
            dred[2][tid] += dred[2][tid + s];
            dred[3][tid] += dred[3][tid + s];
            unsigned a1 = fm1[tid], a2 = fm2[tid];
            merge2(a1, a2, fm1[tid + s], fm2[tid + s]);
            fm1[tid] = a1; fm2[tid] = a2;
        }
        __syncthreads();
    }
    if (tid == 0) {
        double loc = dred[0][0];
        const double hit = dred[1][0], noobj = dred[2][0], cls = dred[3][0];
        const unsigned mm[2] = { fm1[0], fm2[0] };
        // first two responsible boxes (global flat order) use plain instead of sq
#pragma unroll
        for (int s = 0; s < 2; ++s) {
            const unsigned idx = mm[s];
            if (idx != 0xFFFFFFFFu) {
                const int cell = (int)(idx >> 1);
                const int b    = (int)(idx & 1u);
                const float* p = pred + (size_t)cell * 30 + 2 + 4*b;
                const float* t = targ + (size_t)cell * 30 + 2 + 4*b;
                float plain = 0.0f, sq = 0.0f;
#pragma unroll
                for (int i = 0; i < 4; ++i) {
                    const float a = p[i], g = t[i];
                    const float dd = a - g;  plain = fmaf(dd, dd, plain);
                    const float ds = sqrtf(a) - sqrtf(g); sq = fmaf(ds, ds, sq);
                }
                loc += (double)plain - (double)sq;
            }
        }
        const double total = (5.0 * loc + hit + 0.5 * noobj + cls) / 16384.0;
        out[0] = (float)total;
    }
}

extern "C" void kernel_launch(void* const* d_in, const int* in_sizes, int n_in,
                              void* d_out, int out_size, void* d_ws, size_t ws_size,
                              hipStream_t stream) {
    const float* pred = (const float*)d_in[0];
    const float* targ = (const float*)d_in[1];
    float* out = (float*)d_out;

    float* ws_sums = (float*)d_ws;                                        // 4*GBLK floats
    unsigned* ws_mins = (unsigned*)((char*)d_ws + sizeof(float) * 4 * GBLK);  // 2*GBLK uints

    yolo_main_kernel<<<GBLK, 256, 0, stream>>>(pred, targ, ws_sums, ws_mins);
    yolo_finalize_kernel<<<1, 1024, 0, stream>>>(pred, targ, ws_sums, ws_mins, out);
}